// Round 1
// baseline (361.717 us; speedup 1.0000x reference)
//
#include <hip/hip_runtime.h>
#include <math.h>

// Problem: n=256 samples, d=64. All inputs fp32.
// d_in: [0]=t(scalar,unused) [1]=x(256*64) [2]=v(256*64) [3]=W1(64*64)
//       [4]=b1(64) [5]=W2(4096*64) [6]=b2(4096) [7]=W3(64*128)
// out: 256*64 fp32.
//
// Math restructuring:
//   h = tanh(x W1^T + b1); s = 1-h^2; K[m][l] = s[m]*W1[m][l]
//   W2s[i][j][m] = W2[(i*64+j)][m] + W2[(j*64+i)][m]   (symmetric in i,j)
//   Ji = W2s_i @ K  (64x64)  =>  J[i,j,l] = Ji[j][l],  J[l,i,j] = Ji[l][j]
//   q[l] = sum_i v_i sum_j v_j Ji[j][l]^2 Ji[l][j]
//   g[i][j] = sum_m W2s[i][j][m] h[m] + b2[i*64+j] + b2[j*64+i]
//   dv = 0.5 * solve(g, q)          (replaces linalg.inv)
//   out = v @ W3[:, :64]^T + dv @ W3[:, 64:]^T

__global__ __launch_bounds__(256) void prep_w2s_kernel(const float* __restrict__ W2,
                                                       float* __restrict__ W2sA) {
  // W2sA layout: [i][m][j]  (so the j-index is contiguous for coalesced/vector reads)
  int idx = blockIdx.x * 256 + threadIdx.x;   // 0 .. 262143
  int i = idx >> 12;
  int m = (idx >> 6) & 63;
  int j = idx & 63;
  W2sA[idx] = W2[(((i << 6) + j) << 6) + m] + W2[(((j << 6) + i) << 6) + m];
}

__global__ __launch_bounds__(256) void conn_kernel(
    const float* __restrict__ x, const float* __restrict__ v,
    const float* __restrict__ W1, const float* __restrict__ b1,
    const float* __restrict__ b2, const float* __restrict__ W3,
    const float* __restrict__ W2sA, float* __restrict__ out) {
  __shared__ __align__(16) float sK[64][64];     // K[m][l]
  __shared__ __align__(16) float buf[64 * 65];   // phase A: W2s slab [m][j] (64x64); phase B: Ji padded [j][65]
  __shared__ float sg[64][65];                   // g, padded (elimination column reads)
  __shared__ float sh[64], sv[64], sx[64], sq[64], sz[64];
  __shared__ float spart[64][4];

  const int n = blockIdx.x;
  const int t = threadIdx.x;

  if (t < 64) { sx[t] = x[(n << 6) + t]; sv[t] = v[(n << 6) + t]; }
  __syncthreads();

  // h = tanh(x @ W1^T + b1)
  if (t < 64) {
    float acc = b1[t];
    #pragma unroll 8
    for (int l = 0; l < 64; ++l) acc += sx[l] * W1[(t << 6) + l];
    sh[t] = tanhf(acc);
  }
  __syncthreads();

  // K[m][l] = (1-h[m]^2) * W1[m][l]
  for (int e = t; e < 4096; e += 256) {
    int m = e >> 6, l = e & 63;
    float hm = sh[m];
    sK[m][l] = (1.f - hm * hm) * W1[(m << 6) + l];
  }
  // g[i][j] = sum_m W2sA[i][m][j]*h[m] + b2[i*64+j] + b2[j*64+i]  (W2sA is L2-resident)
  for (int e = t; e < 4096; e += 256) {
    int i = e >> 6, j = e & 63;
    float acc = b2[(i << 6) + j] + b2[(j << 6) + i];
    const float* wp = W2sA + (i << 12) + j;
    #pragma unroll 8
    for (int m = 0; m < 64; ++m) acc += wp[m << 6] * sh[m];
    sg[i][j] = acc;
  }

  const int tj = t >> 4, tl = t & 15;   // 16x16 thread grid over 4x4 output tiles
  const int lq = t >> 2, jq = t & 3;    // contraction assignment: l=lq, j-quarter=jq
  float part = 0.f;

  for (int i = 0; i < 64; ++i) {
    __syncthreads();  // prior iter's reads of buf done
    {  // stage W2s slab i ([m][j], 16KB) into buf; coalesced float4
      const float4* src = (const float4*)(W2sA + (i << 12));
      float4* dst = (float4*)buf;
      dst[t]       = src[t];
      dst[t + 256] = src[t + 256];
      dst[t + 512] = src[t + 512];
      dst[t + 768] = src[t + 768];
    }
    __syncthreads();

    // Ji[j][l] = sum_m slab[m][j] * K[m][l]; each thread a 4x4 tile
    float acc[4][4];
    #pragma unroll
    for (int a = 0; a < 4; ++a)
      #pragma unroll
      for (int b = 0; b < 4; ++b) acc[a][b] = 0.f;

    #pragma unroll 4
    for (int m = 0; m < 64; ++m) {
      float4 wj = *(const float4*)(buf + (m << 6) + (tj << 2));
      float4 kl = *(const float4*)(&sK[m][tl << 2]);
      acc[0][0] += wj.x * kl.x; acc[0][1] += wj.x * kl.y; acc[0][2] += wj.x * kl.z; acc[0][3] += wj.x * kl.w;
      acc[1][0] += wj.y * kl.x; acc[1][1] += wj.y * kl.y; acc[1][2] += wj.y * kl.z; acc[1][3] += wj.y * kl.w;
      acc[2][0] += wj.z * kl.x; acc[2][1] += wj.z * kl.y; acc[2][2] += wj.z * kl.z; acc[2][3] += wj.z * kl.w;
      acc[3][0] += wj.w * kl.x; acc[3][1] += wj.w * kl.y; acc[3][2] += wj.w * kl.z; acc[3][3] += wj.w * kl.w;
    }
    __syncthreads();  // all slab reads done before overwriting buf as Ji

    #pragma unroll
    for (int a = 0; a < 4; ++a)
      #pragma unroll
      for (int b = 0; b < 4; ++b)
        buf[((tj << 2) + a) * 65 + (tl << 2) + b] = acc[a][b];
    __syncthreads();

    // q[l] partial: sum_j v_j * Ji[j][l]^2 * Ji[l][j], this thread: l=lq, j in [16*jq, 16*jq+16)
    float ssum = 0.f;
    const int j0 = jq << 4;
    #pragma unroll 8
    for (int jj = 0; jj < 16; ++jj) {
      int j = j0 + jj;
      float Jjl = buf[j * 65 + lq];
      float Jlj = buf[lq * 65 + j];
      ssum += sv[j] * Jjl * Jjl * Jlj;
    }
    part += sv[i] * ssum;
  }

  spart[lq][jq] = part;
  __syncthreads();
  if (t < 64) sq[t] = spart[t][0] + spart[t][1] + spart[t][2] + spart[t][3];

  // Solve g z = q. Gaussian elimination, no pivoting (g ~ 6I + small perturbation, SPD).
  const int r = t & 63, cg = t >> 6;  // 4 column groups of 16
  for (int p = 0; p < 63; ++p) {
    __syncthreads();
    if (r > p) {
      float f = sg[r][p] / sg[p][p];
      int c0 = cg << 4;
      int c1 = c0 + 16;
      if (c0 <= p) c0 = p + 1;
      for (int c = c0; c < c1; ++c) sg[r][c] -= f * sg[p][c];
      if (cg == 0) sq[r] -= f * sq[p];
    }
  }
  // Back substitution (column-oriented)
  for (int p = 63; p >= 0; --p) {
    __syncthreads();
    if (t == 0) sz[p] = sq[p] / sg[p][p];
    __syncthreads();
    if (t < p) sq[t] -= sg[t][p] * sz[p];
  }

  // out[n][k] = sum_c v[c]*W3[k][c] + 0.5*z[c]*W3[k][64+c]
  if (t < 64) {
    float accv = 0.f, accd = 0.f;
    #pragma unroll 8
    for (int c = 0; c < 64; ++c) {
      accv += sv[c] * W3[(t << 7) + c];
      accd += sz[c] * W3[(t << 7) + 64 + c];
    }
    out[(n << 6) + t] = accv + 0.5f * accd;
  }
}

extern "C" void kernel_launch(void* const* d_in, const int* in_sizes, int n_in,
                              void* d_out, int out_size, void* d_ws, size_t ws_size,
                              hipStream_t stream) {
  (void)in_sizes; (void)n_in; (void)out_size; (void)ws_size;
  const float* x  = (const float*)d_in[1];
  const float* v  = (const float*)d_in[2];
  const float* W1 = (const float*)d_in[3];
  const float* b1 = (const float*)d_in[4];
  const float* W2 = (const float*)d_in[5];
  const float* b2 = (const float*)d_in[6];
  const float* W3 = (const float*)d_in[7];
  float* W2sA = (float*)d_ws;  // 64*64*64 floats = 1 MB scratch

  hipLaunchKernelGGL(prep_w2s_kernel, dim3(1024), dim3(256), 0, stream, W2, W2sA);
  hipLaunchKernelGGL(conn_kernel, dim3(256), dim3(256), 0, stream,
                     x, v, W1, b1, b2, W3, W2sA, (float*)d_out);
}

// Round 2
// 110.773 us; speedup vs baseline: 3.2654x; 3.2654x over previous
//
#include <hip/hip_runtime.h>
#include <math.h>
#include <stdint.h>

// n=256 samples, d=64, fp32 in/out. J-path in bf16 MFMA (error budget: dv
// contributes ~1e-4 to O(1) outputs; threshold 5.8e-2).
//
//   h = tanh(x W1^T + b1); K[m][l] = (1-h^2)[m] W1[m][l]
//   W2sB[i][j][m] = bf16(W2[(i,j)][m] + W2[(j,i)][m])   (symmetric in i,j)
//   Ji = W2sB_i @ K   (64x64, MFMA; A-frags straight from L2, B-frags = K^T
//        in LDS, hoisted out of the i-loop)
//   ext column 64 of B = h  =>  C col 64 = g-row i (Sum_m W2s[i,j,m] h[m])
//   q[l] = Sum_i v_i Sum_j v_j Ji[j][l]^2 Ji[l][j]   (Ji^T staged in LDS,
//        double-buffered, 1 barrier per i)
//   g = ext + b2 + b2^T;  z = g^{-1} q via 20 Jacobi sweeps (g ~ 6I + E,
//        rho ~ 0.37);  out = v@W3[:, :64]^T + 0.5 z@W3[:, 64:]^T

typedef short short8 __attribute__((ext_vector_type(8)));
typedef float f32x4 __attribute__((ext_vector_type(4)));

__device__ __forceinline__ unsigned short f2bf(float f) {
  unsigned int u = __builtin_bit_cast(unsigned int, f);
  u += 0x7fffu + ((u >> 16) & 1u);
  return (unsigned short)(u >> 16);
}

__device__ __forceinline__ short8 as_short8(uint4 u) {
  union { uint4 a; short8 b; } cv; cv.a = u; return cv.b;
}

__global__ __launch_bounds__(256) void prep_w2s_kernel(const float* __restrict__ W2,
                                                       unsigned short* __restrict__ W2sB) {
  int idx = blockIdx.x * 256 + threadIdx.x;           // [i][j][m]
  int i = idx >> 12, j = (idx >> 6) & 63, m = idx & 63;
  W2sB[idx] = f2bf(W2[(((i << 6) + j) << 6) + m] + W2[(((j << 6) + i) << 6) + m]);
}

__global__ __launch_bounds__(256) void conn_kernel(
    const float* __restrict__ x, const float* __restrict__ v,
    const float* __restrict__ W1, const float* __restrict__ b1,
    const float* __restrict__ b2, const float* __restrict__ W3,
    const unsigned short* __restrict__ W2sB, float* __restrict__ out) {
  __shared__ __align__(16) unsigned short sKT[80 * 80];  // [n'][m] bf16: rows 0-63 = K^T, row 64 = h, 65-79 = 0
  __shared__ __align__(16) float jit[2][64 * 68];        // Ji transposed: value Ji[a][b] at [b*68+a]
  __shared__ float sg[64 * 65];                          // g (stride 65: conflict-free row reads)
  __shared__ float spq[64 * 16];
  __shared__ float sh[64], sv[64], sx[64], sq[64], sz[64];

  const int n = blockIdx.x, t = threadIdx.x;
  const int wv = t >> 6, lane = t & 63, ln15 = lane & 15, quad = lane >> 4;
  const int j0 = 16 * wv + 4 * quad;   // C-frag rows for this thread
  const int arow = 16 * wv + ln15;     // A-frag row (output row j)

  if (t < 64) { sx[t] = x[(n << 6) + t]; sv[t] = v[(n << 6) + t]; }
  for (int e = t; e < 6400; e += 256) sKT[e] = 0;
  __syncthreads();

  if (t < 64) {
    float acc = b1[t];
    #pragma unroll 8
    for (int l = 0; l < 64; ++l) acc += sx[l] * W1[(t << 6) + l];
    sh[t] = tanhf(acc);
  }
  __syncthreads();

  for (int e = t; e < 4096; e += 256) {
    int m = e & 63, l = e >> 6;
    float hm = sh[m];
    sKT[l * 80 + m] = f2bf((1.f - hm * hm) * W1[(m << 6) + l]);
  }
  if (t < 64) sKT[64 * 80 + t] = f2bf(sh[t]);
  __syncthreads();

  // B-frags: resident for whole i-loop. Tile lc covers cols lc*16+ln15.
  short8 bf[5][2];
  #pragma unroll
  for (int lc = 0; lc < 5; ++lc)
    #pragma unroll
    for (int ks = 0; ks < 2; ++ks)
      bf[lc][ks] = *(const short8*)&sKT[(lc * 16 + ln15) * 80 + ks * 32 + quad * 8];

  float svj[4];
  #pragma unroll
  for (int r = 0; r < 4; ++r) svj[r] = sv[j0 + r];

  f32x4 c[5];
  float qacc[4] = {0.f, 0.f, 0.f, 0.f};

  const unsigned short* abase = W2sB + (arow << 6) + quad * 8;
  uint4 a0 = *(const uint4*)(abase);        // i=0, ks=0
  uint4 a1 = *(const uint4*)(abase + 32);   // i=0, ks=1

  for (int i = 0; i < 64; ++i) {
    const unsigned short* anext = abase + (((size_t)((i + 1) & 63)) << 12);
    uint4 an0 = *(const uint4*)(anext);
    uint4 an1 = *(const uint4*)(anext + 32);

    if (i > 0) {  // contract C(i-1): q[l] += v_{i-1} * sum_j v_j Ji[j][l]^2 Ji[l][j]
      const float* jp = jit[(i - 1) & 1];
      float vi = sv[i - 1];
      #pragma unroll
      for (int lc = 0; lc < 4; ++lc) {
        float acc = 0.f;
        #pragma unroll
        for (int r = 0; r < 4; ++r) {
          float cj = c[lc][r];
          float jt = jp[(j0 + r) * 68 + lc * 16 + ln15];  // Ji[l][j]
          acc += svj[r] * cj * cj * jt;
        }
        qacc[lc] += vi * acc;
      }
    }

    short8 A0 = as_short8(a0), A1 = as_short8(a1);
    #pragma unroll
    for (int lc = 0; lc < 5; ++lc) {
      f32x4 z4 = {0.f, 0.f, 0.f, 0.f};
      f32x4 cc = __builtin_amdgcn_mfma_f32_16x16x32_bf16(A0, bf[lc][0], z4, 0, 0, 0);
      c[lc]    = __builtin_amdgcn_mfma_f32_16x16x32_bf16(A1, bf[lc][1], cc, 0, 0, 0);
    }

    float* jw = jit[i & 1];
    #pragma unroll
    for (int lc = 0; lc < 4; ++lc)   // store transposed: regs = 4 consecutive j -> b128
      *(f32x4*)&jw[(lc * 16 + ln15) * 68 + j0] = c[lc];
    if (ln15 == 0) {                 // ext tile col 64 = g-row i
      #pragma unroll
      for (int r = 0; r < 4; ++r) sg[i * 65 + j0 + r] = c[4][r];
    }
    __syncthreads();
    a0 = an0; a1 = an1;
  }

  {  // contract C(63)
    const float* jp = jit[1];
    float vi = sv[63];
    #pragma unroll
    for (int lc = 0; lc < 4; ++lc) {
      float acc = 0.f;
      #pragma unroll
      for (int r = 0; r < 4; ++r) {
        float cj = c[lc][r];
        float jt = jp[(j0 + r) * 68 + lc * 16 + ln15];
        acc += svj[r] * cj * cj * jt;
      }
      qacc[lc] += vi * acc;
    }
  }
  #pragma unroll
  for (int lc = 0; lc < 4; ++lc)
    spq[(lc * 16 + ln15) * 16 + (wv * 4 + quad)] = qacc[lc];

  for (int e = t; e < 4096; e += 256) {   // g += b2 + b2^T
    int r = e >> 6, cc2 = e & 63;
    sg[r * 65 + cc2] += b2[(r << 6) + cc2] + b2[(cc2 << 6) + r];
  }
  __syncthreads();

  if (t < 64) {
    float s = 0.f;
    #pragma unroll
    for (int e2 = 0; e2 < 16; ++e2) s += spq[t * 16 + e2];
    sq[t] = s;
    sz[t] = s / sg[t * 65 + t];   // Jacobi init
  }
  __syncthreads();

  // Jacobi: z' = z + (q - g z)/diag. Thread: row r = 16*wv+ln15, col-group = quad.
  {
    const int r = 16 * wv + ln15;
    const float* grow = &sg[r * 65];
    const float dinv = 1.f / grow[r];
    const float qr = sq[r];
    for (int it = 0; it < 20; ++it) {
      float p = 0.f;
      #pragma unroll
      for (int cc2 = 0; cc2 < 16; ++cc2) {
        int cidx = quad * 16 + cc2;
        p += grow[cidx] * sz[cidx];
      }
      p += __shfl_xor(p, 16, 64);
      p += __shfl_xor(p, 32, 64);
      float zr = 0.f;
      if (quad == 0) zr = sz[r] + (qr - p) * dinv;
      __syncthreads();
      if (quad == 0) sz[r] = zr;
      __syncthreads();
    }
  }

  if (t < 64) {
    float accv = 0.f, accd = 0.f;
    #pragma unroll 8
    for (int c2 = 0; c2 < 64; ++c2) {
      accv += sv[c2] * W3[(t << 7) + c2];
      accd += sz[c2] * W3[(t << 7) + 64 + c2];
    }
    out[(n << 6) + t] = accv + 0.5f * accd;
  }
}

extern "C" void kernel_launch(void* const* d_in, const int* in_sizes, int n_in,
                              void* d_out, int out_size, void* d_ws, size_t ws_size,
                              hipStream_t stream) {
  (void)in_sizes; (void)n_in; (void)out_size; (void)ws_size;
  const float* x  = (const float*)d_in[1];
  const float* v  = (const float*)d_in[2];
  const float* W1 = (const float*)d_in[3];
  const float* b1 = (const float*)d_in[4];
  const float* W2 = (const float*)d_in[5];
  const float* b2 = (const float*)d_in[6];
  const float* W3 = (const float*)d_in[7];
  unsigned short* W2sB = (unsigned short*)d_ws;  // 64*64*64 bf16 = 512 KB

  hipLaunchKernelGGL(prep_w2s_kernel, dim3(1024), dim3(256), 0, stream, W2, W2sB);
  hipLaunchKernelGGL(conn_kernel, dim3(256), dim3(256), 0, stream,
                     x, v, W1, b1, b2, W3, W2sB, (float*)d_out);
}

// Round 3
// 103.029 us; speedup vs baseline: 3.5108x; 1.0752x over previous
//
#include <hip/hip_runtime.h>
#include <math.h>
#include <stdint.h>

// n=256 samples, d=64, fp32 in/out. J-path bf16 MFMA.
//   K[m][l] = (1-h^2)[m] W1[m][l];  sKT[l][m] = K[m][l] (bf16), row 64 = h
//   W2sB[i][j][m] = bf16(W2[(i,j)][m] + W2[(j,i)][m])  (symmetric in i,j)
//   slab-frag af[t] (rows of W2s_i) and sKT-frag bf[t] are BOTH valid as A or B:
//     C1 = mfma(A=af[tr], B=bf[tc]) -> Ji[j][l]       (j=row, l=col)
//     C2 = mfma(A=bf[tr], B=af[tc]) -> Ji[l][j]       at the SAME (lane,reg)!
//   => q[l] += v_i * v_j * C1^2 * C2 fully in-register; no LDS transpose,
//      no barriers in the i-loop. Each wave owns 16 i's independently.
//   g-row i via ext B-frag (sKT row 64 = h); g += b2 + b2^T; 20 Jacobi sweeps;
//   out = v@W3[:,:64]^T + 0.5 z@W3[:,64:]^T.

typedef short short8 __attribute__((ext_vector_type(8)));
typedef float f32x4 __attribute__((ext_vector_type(4)));

__device__ __forceinline__ unsigned short f2bf(float f) {
  unsigned int u = __builtin_bit_cast(unsigned int, f);
  u += 0x7fffu + ((u >> 16) & 1u);
  return (unsigned short)(u >> 16);
}

__device__ __forceinline__ short8 as_short8(uint4 u) {
  union { uint4 a; short8 b; } cv; cv.a = u; return cv.b;
}

__global__ __launch_bounds__(256) void prep_w2s_kernel(const float* __restrict__ W2,
                                                       unsigned short* __restrict__ W2sB) {
  int idx = blockIdx.x * 256 + threadIdx.x;           // [i][j][m]
  int i = idx >> 12, j = (idx >> 6) & 63, m = idx & 63;
  W2sB[idx] = f2bf(W2[(((i << 6) + j) << 6) + m] + W2[(((j << 6) + i) << 6) + m]);
}

__global__ __launch_bounds__(256, 1) void conn_kernel(
    const float* __restrict__ x, const float* __restrict__ v,
    const float* __restrict__ W1, const float* __restrict__ b1,
    const float* __restrict__ b2, const float* __restrict__ W3,
    const unsigned short* __restrict__ W2sB, float* __restrict__ out) {
  __shared__ __align__(16) unsigned short sKT[80 * 80];  // rows 0-63 = K^T, 64 = h, 65-79 = 0
  __shared__ __align__(16) float sg[64 * 68];            // g, stride 68 (f32x4-aligned stores)
  __shared__ float spq[4][64];
  __shared__ __align__(16) float sh[64], sv[64], sx[64], sq[64], sz[64];

  const int n = blockIdx.x, t = threadIdx.x;
  const int wv = t >> 6, lane = t & 63, ln15 = lane & 15, quad = lane >> 4;

  if (t < 64) { sx[t] = x[(n << 6) + t]; sv[t] = v[(n << 6) + t]; }
  for (int e = t; e < 6400; e += 256) sKT[e] = 0;
  __syncthreads();

  if (t < 64) {
    float acc = b1[t];
    #pragma unroll 8
    for (int l = 0; l < 64; ++l) acc += sx[l] * W1[(t << 6) + l];
    sh[t] = tanhf(acc);
  }
  __syncthreads();

  for (int e = t; e < 4096; e += 256) {
    int m = e & 63, l = e >> 6;
    float hm = sh[m];
    sKT[l * 80 + m] = f2bf((1.f - hm * hm) * W1[(m << 6) + l]);
  }
  if (t < 64) sKT[64 * 80 + t] = f2bf(sh[t]);
  __syncthreads();

  // sKT frags: tiles 0..3 dual-use (A for C2 row-tile / B for C1 col-tile), tile 4 = ext (h)
  short8 bf[5][2];
  #pragma unroll
  for (int tc = 0; tc < 5; ++tc)
    #pragma unroll
    for (int ks = 0; ks < 2; ++ks)
      bf[tc][ks] = *(const short8*)&sKT[(tc * 16 + ln15) * 80 + ks * 32 + quad * 8];

  f32x4 svj[4];
  #pragma unroll
  for (int tr = 0; tr < 4; ++tr) svj[tr] = *(const f32x4*)&sv[tr * 16 + quad * 4];

  float qacc[4] = {0.f, 0.f, 0.f, 0.f};

  // Wave wv owns i in [16*wv, 16*wv+16). Slab frags: dual-use A(C1)/B(C2).
  const int foff = (ln15 << 6) + quad * 8;  // within-slab frag offset for tile row/col base
  const unsigned short* sbase = W2sB + ((size_t)(16 * wv) << 12);

  uint4 af[4][2], afn[4][2];
  #pragma unroll
  for (int tc = 0; tc < 4; ++tc) {
    af[tc][0] = *(const uint4*)(sbase + (tc << 10) + foff);
    af[tc][1] = *(const uint4*)(sbase + (tc << 10) + foff + 32);
  }

  for (int ii = 0; ii < 16; ++ii) {
    const unsigned short* spn = W2sB + ((size_t)(16 * wv + ((ii + 1) & 15)) << 12);
    #pragma unroll
    for (int tc = 0; tc < 4; ++tc) {
      afn[tc][0] = *(const uint4*)(spn + (tc << 10) + foff);
      afn[tc][1] = *(const uint4*)(spn + (tc << 10) + foff + 32);
    }
    const int i = 16 * wv + ii;
    const float vi = sv[i];

    #pragma unroll
    for (int tr = 0; tr < 4; ++tr) {
      short8 a0 = as_short8(af[tr][0]), a1 = as_short8(af[tr][1]);
      f32x4 c1[4], c2[4], ce;
      #pragma unroll
      for (int tc = 0; tc < 4; ++tc) {
        f32x4 z4 = {0.f, 0.f, 0.f, 0.f};
        f32x4 u = __builtin_amdgcn_mfma_f32_16x16x32_bf16(a0, bf[tc][0], z4, 0, 0, 0);
        c1[tc]  = __builtin_amdgcn_mfma_f32_16x16x32_bf16(a1, bf[tc][1], u, 0, 0, 0);
        f32x4 w = __builtin_amdgcn_mfma_f32_16x16x32_bf16(bf[tr][0], as_short8(af[tc][0]), z4, 0, 0, 0);
        c2[tc]  = __builtin_amdgcn_mfma_f32_16x16x32_bf16(bf[tr][1], as_short8(af[tc][1]), w, 0, 0, 0);
      }
      {
        f32x4 z4 = {0.f, 0.f, 0.f, 0.f};
        f32x4 u = __builtin_amdgcn_mfma_f32_16x16x32_bf16(a0, bf[4][0], z4, 0, 0, 0);
        ce      = __builtin_amdgcn_mfma_f32_16x16x32_bf16(a1, bf[4][1], u, 0, 0, 0);
      }
      if (ln15 == 0)  // g[i][j], j = 16*tr + 4*quad + r; stride 68 keeps 16B alignment
        *(f32x4*)&sg[i * 68 + tr * 16 + quad * 4] = ce;

      #pragma unroll
      for (int tc = 0; tc < 4; ++tc) {
        float s = 0.f;
        #pragma unroll
        for (int r = 0; r < 4; ++r) {
          float a = c1[tc][r];
          s = fmaf(a * a * c2[tc][r], svj[tr][r], s);
        }
        qacc[tc] = fmaf(s, vi, qacc[tc]);
      }
    }
    #pragma unroll
    for (int tc = 0; tc < 4; ++tc) { af[tc][0] = afn[tc][0]; af[tc][1] = afn[tc][1]; }
  }

  // reduce qacc over quads (rows j), publish per-wave partial q
  #pragma unroll
  for (int tc = 0; tc < 4; ++tc) {
    float s = qacc[tc];
    s += __shfl_xor(s, 16, 64);
    s += __shfl_xor(s, 32, 64);
    if (quad == 0) spq[wv][tc * 16 + ln15] = s;
  }
  __syncthreads();  // first block-wide sync since setup

  for (int e = t; e < 4096; e += 256) {   // g += b2 + b2^T
    int r = e >> 6, c = e & 63;
    sg[r * 68 + c] += b2[(r << 6) + c] + b2[(c << 6) + r];
  }
  __syncthreads();

  if (t < 64) {
    float s = spq[0][t] + spq[1][t] + spq[2][t] + spq[3][t];
    sq[t] = s;
    sz[t] = s / sg[t * 68 + t];   // Jacobi init
  }
  __syncthreads();

  // Jacobi: z' = z + (q - g z)/diag; row r = 16*wv+ln15, col-group = quad
  {
    const int r = 16 * wv + ln15;
    const float* grow = &sg[r * 68];
    const float dinv = 1.f / grow[r];
    const float qr = sq[r];
    for (int it = 0; it < 20; ++it) {
      float p = 0.f;
      #pragma unroll
      for (int cc = 0; cc < 16; ++cc) {
        int cidx = quad * 16 + cc;
        p += grow[cidx] * sz[cidx];
      }
      p += __shfl_xor(p, 16, 64);
      p += __shfl_xor(p, 32, 64);
      float zr = 0.f;
      if (quad == 0) zr = sz[r] + (qr - p) * dinv;
      __syncthreads();
      if (quad == 0) sz[r] = zr;
      __syncthreads();
    }
  }

  if (t < 64) {
    float accv = 0.f, accd = 0.f;
    #pragma unroll 8
    for (int c = 0; c < 64; ++c) {
      accv += sv[c] * W3[(t << 7) + c];
      accd += sz[c] * W3[(t << 7) + 64 + c];
    }
    out[(n << 6) + t] = accv + 0.5f * accd;
  }
}

extern "C" void kernel_launch(void* const* d_in, const int* in_sizes, int n_in,
                              void* d_out, int out_size, void* d_ws, size_t ws_size,
                              hipStream_t stream) {
  (void)in_sizes; (void)n_in; (void)out_size; (void)ws_size;
  const float* x  = (const float*)d_in[1];
  const float* v  = (const float*)d_in[2];
  const float* W1 = (const float*)d_in[3];
  const float* b1 = (const float*)d_in[4];
  const float* W2 = (const float*)d_in[5];
  const float* b2 = (const float*)d_in[6];
  const float* W3 = (const float*)d_in[7];
  unsigned short* W2sB = (unsigned short*)d_ws;  // 64*64*64 bf16 = 512 KB

  hipLaunchKernelGGL(prep_w2s_kernel, dim3(1024), dim3(256), 0, stream, W2, W2sB);
  hipLaunchKernelGGL(conn_kernel, dim3(256), dim3(256), 0, stream,
                     x, v, W1, b1, b2, W3, W2sB, (float*)d_out);
}